// Round 1
// baseline (258.578 us; speedup 1.0000x reference)
//
#include <hip/hip_runtime.h>
#include <cstdint>
#include <cstddef>

typedef unsigned short u16;
typedef unsigned int   u32;

typedef short bf16x8 __attribute__((ext_vector_type(8)));
typedef float f32x4  __attribute__((ext_vector_type(4)));

// ---------------- helpers ----------------
__device__ __forceinline__ u16 f2bf(float f) {   // RNE f32 -> bf16
  u32 u = __float_as_uint(f);
  u += 0x7fffu + ((u >> 16) & 1u);
  return (u16)(u >> 16);
}
__device__ __forceinline__ float bflo(u32 w) { return __uint_as_float((w & 0xffffu) << 16); }
__device__ __forceinline__ float bfhi(u32 w) { return __uint_as_float(w & 0xffff0000u); }

#define GLB_AS(p) ((const __attribute__((address_space(1))) void*)(p))
#define LDS_AS(p) ((__attribute__((address_space(3))) void*)(p))

// ---------------- fused f32 -> bf16 convert: inputs + Wi + Wo ----------------
// quads: inputs 4194304, Wi 131072, Wo 131072 -> 17408 blocks x 256 exactly.
__global__ __launch_bounds__(256)
void conv3_f32_bf16(const float* __restrict__ in, u16* __restrict__ a,
                    const float* __restrict__ wi, u16* __restrict__ wib,
                    const float* __restrict__ wo, u16* __restrict__ wob)
{
  long i = (long)blockIdx.x * 256 + threadIdx.x;
  const float* src; u16* dst;
  if (i < 4194304L) { src = in; dst = a; }
  else if (i < 4325376L) { i -= 4194304L; src = wi; dst = wib; }
  else { i -= 4325376L; if (i >= 131072L) return; src = wo; dst = wob; }
  float4 v = ((const float4*)src)[i];
  u32 lo = (u32)f2bf(v.x) | ((u32)f2bf(v.y) << 16);
  u32 hi = (u32)f2bf(v.z) | ((u32)f2bf(v.w) << 16);
  ((uint2*)dst)[i] = make_uint2(lo, hi);
}

// ---------------- bf16 GEMM, 256x128 tile, BK=32, 512 thr, XCD-local --------
// C[m,n] = sum_k A[m,k] * W[n,k]  (A: MxK row-major, W: NxK row-major).
// R6 post-mortem: all 128x128 variants stage 512 MB and land at 505 TF
// (7.5 TB/s staging-path ceiling). This tile stages (256+128)/(256*128) =
// 25% fewer bytes/FLOP -> 384 MB total. Per-wave geometry is byte-identical
// to the validated R2 kernel: 8 waves (4m x 2n) of 64x64, 4x4 acc, BK=32,
// R2's conflict-free granule swizzle (r>>1 XOR), same fragment maps.
// XCD swizzle kept (R5/R6-validated): xcd=bid&7, n-inner per XCD.
template<int N, int K, int LOGNB, int OUT_BF16, int RELU>
__global__ __launch_bounds__(512, 4)
void gemm_w2(const u16* __restrict__ A, const u16* __restrict__ Bw,
             const float* __restrict__ bias, void* __restrict__ Cout)
{
  __shared__ __align__(16) u16 As[256 * 32];   // 16 KB
  __shared__ __align__(16) u16 Bs[128 * 32];   //  8 KB

  const int tid  = threadIdx.x;
  const int lane = tid & 63;
  const int wave = tid >> 6;
  const int bid  = blockIdx.x;
  const int xcd  = bid & 7;
  const int s    = bid >> 3;
  const int m0 = (xcd * 16 + (s >> LOGNB)) * 256;
  const int n0 = (s & ((1 << LOGNB) - 1)) * 128;
  const int wm = (wave & 3) * 64;
  const int wn = (wave >> 2) * 64;

  f32x4 acc[4][4];
#pragma unroll
  for (int i = 0; i < 4; ++i)
#pragma unroll
    for (int j = 0; j < 4; ++j) acc[i][j] = f32x4{0.f, 0.f, 0.f, 0.f};

  // DMA staging (granule = 16 B; 4 granules per 32-k row; R2 swizzle):
  // A: 1024 granules -> 2 instrs; B: 512 granules -> 1 instr.
  const u16* Ap[2]; const u16* Bp; int ldsA[2]; int ldsB;
#pragma unroll
  for (int i = 0; i < 2; ++i) {
    int g = i * 512 + tid;
    int r = g >> 2;
    int koff = ((g & 3) ^ ((r >> 1) & 3)) << 3;
    Ap[i]   = A + (size_t)(m0 + r) * K + koff;
    ldsA[i] = (i * 512 + wave * 64) * 8;        // wave-uniform base (u16)
  }
  {
    int g = tid;
    int r = g >> 2;
    int koff = ((g & 3) ^ ((r >> 1) & 3)) << 3;
    Bp   = Bw + (size_t)(n0 + r) * K + koff;
    ldsB = (wave * 64) * 8;
  }

  // fragment granule offsets (R2-validated map)
  const int fm = lane & 15;
  const int q  = lane >> 4;
  int aoff[4], boff[4];
#pragma unroll
  for (int i = 0; i < 4; ++i) {
    int m = wm + i * 16 + fm;
    aoff[i] = (m * 4 + (q ^ ((m >> 1) & 3))) * 8;
    int n = wn + i * 16 + fm;
    boff[i] = (n * 4 + (q ^ ((n >> 1) & 3))) * 8;
  }

  for (int kt = 0; kt < K; kt += 32) {
    __builtin_amdgcn_global_load_lds(GLB_AS(Ap[0] + kt), LDS_AS(As + ldsA[0]), 16, 0, 0);
    __builtin_amdgcn_global_load_lds(GLB_AS(Ap[1] + kt), LDS_AS(As + ldsA[1]), 16, 0, 0);
    __builtin_amdgcn_global_load_lds(GLB_AS(Bp    + kt), LDS_AS(Bs + ldsB),    16, 0, 0);
    __syncthreads();  // drain: tile visible

    bf16x8 af[4], bf[4];
#pragma unroll
    for (int i = 0; i < 4; ++i) { af[i] = *(const bf16x8*)&As[aoff[i]];
                                  bf[i] = *(const bf16x8*)&Bs[boff[i]]; }
#pragma unroll
    for (int mi = 0; mi < 4; ++mi)
#pragma unroll
      for (int ni = 0; ni < 4; ++ni)
        acc[mi][ni] = __builtin_amdgcn_mfma_f32_16x16x32_bf16(af[mi], bf[ni],
                                                              acc[mi][ni], 0, 0, 0);
    __syncthreads();  // reads done before next tile's DMA overwrites
  }

  // epilogue: C/D layout col=lane&15, row=(lane>>4)*4+reg  (validated R1-R6)
  const int colL = lane & 15;
  const int rowQ = (lane >> 4) * 4;
#pragma unroll
  for (int mi = 0; mi < 4; ++mi) {
#pragma unroll
    for (int ni = 0; ni < 4; ++ni) {
      int col  = n0 + wn + ni * 16 + colL;
      int rowb = m0 + wm + mi * 16 + rowQ;
      float bv = bias[col];
#pragma unroll
      for (int r = 0; r < 4; ++r) {
        float v = acc[mi][ni][r] + bv;
        if (RELU) v = fmaxf(v, 0.f);
        size_t idx = (size_t)(rowb + r) * N + col;
        if (OUT_BF16) ((u16*)Cout)[idx] = f2bf(v);
        else          ((float*)Cout)[idx] = v;
      }
    }
  }
}

// ---------------- scan pass 1: per-chunk end state ----------------
// R7: 128 chunks x 32 steps (was 32 x 128), 2 complex channels/thread.
//  - uint2 (8 B/lane) loads instead of 4 B scalar (G13 vectorization)
//  - 1024 blocks x 4 waves = 4 waves/SIMD (was 2) for latency hiding
//  - two independent recurrence chains/thread (2x ILP on the dep chain)
__global__ __launch_bounds__(256)
void scan_chunk_end(const u16* __restrict__ u, const float* __restrict__ plog,
                    float2* __restrict__ e)
{
  const int t = threadIdx.x;          // channel pair 0..255 (ch 2t, 2t+1)
  const int c = blockIdx.x;           // chunk 0..127 (32 steps each)
  const int b = blockIdx.y;           // batch 0..7
  const int j0 = 2 * t;
  float v0 = expf(plog[j0]),        v1 = expf(plog[j0 + 1]);
  float t0 = expf(plog[512 + j0]),  t1 = expf(plog[512 + j0 + 1]);
  float m0 = expf(-v0), m1 = expf(-v1);
  float lr0 = m0 * cosf(t0), li0 = m0 * sinf(t0);
  float lr1 = m1 * cosf(t1), li1 = m1 * sinf(t1);
  const uint2* up = (const uint2*)u;            // 256 uint2 per row
  size_t idx = (size_t)(b * 4096 + c * 32) * 256 + t;
  float h0r = 0.f, h0i = 0.f, h1r = 0.f, h1i = 0.f;
#pragma unroll 8
  for (int s = 0; s < 32; ++s) {
    uint2 w = up[idx]; idx += 256;
    float u0r = bflo(w.x), u0i = bfhi(w.x);
    float u1r = bflo(w.y), u1i = bfhi(w.y);
    float n0r = fmaf(lr0, h0r, fmaf(-li0, h0i, u0r));
    float n0i = fmaf(lr0, h0i, fmaf( li0, h0r, u0i));
    float n1r = fmaf(lr1, h1r, fmaf(-li1, h1i, u1r));
    float n1i = fmaf(lr1, h1i, fmaf( li1, h1r, u1i));
    h0r = n0r; h0i = n0i; h1r = n1r; h1i = n1i;
  }
  // e layout: [b][c][512] float2 (4 MB); both channels in one float4 store
  ((float4*)e)[(size_t)(b * 128 + c) * 256 + t] = make_float4(h0r, h0i, h1r, h1i);
}

// ---------------- scan pass 2 (fused carry + output) ----------------
__global__ __launch_bounds__(256)
void scan_out2(const u16* __restrict__ u, const float* __restrict__ plog,
               const float2* __restrict__ e, u16* __restrict__ xr)
{
  const int t = threadIdx.x;
  const int c = blockIdx.x;
  const int b = blockIdx.y;
  const int j0 = 2 * t;
  float v0 = expf(plog[j0]),        v1 = expf(plog[j0 + 1]);
  float t0 = expf(plog[512 + j0]),  t1 = expf(plog[512 + j0 + 1]);
  float g0 = expf(plog[1024 + j0]), g1 = expf(plog[1024 + j0 + 1]);
  float m0 = expf(-v0), m1 = expf(-v1);
  float lr0 = m0 * cosf(t0), li0 = m0 * sinf(t0);
  float lr1 = m1 * cosf(t1), li1 = m1 * sinf(t1);

  // carry across chunk-end states: Lambda = lambda^32 (tiny, L2/L3-resident)
  float Lm0 = expf(-32.f * v0), Lm1 = expf(-32.f * v1);
  float La0 = 32.f * t0,        La1 = 32.f * t1;
  float Lr0 = Lm0 * cosf(La0), Li0 = Lm0 * sinf(La0);
  float Lr1 = Lm1 * cosf(La1), Li1 = Lm1 * sinf(La1);
  float h0r = 0.f, h0i = 0.f, h1r = 0.f, h1i = 0.f;
  const float4* e4 = (const float4*)e;
#pragma unroll 4
  for (int i = 0; i < c; ++i) {
    float4 ec = e4[(size_t)(b * 128 + i) * 256 + t];
    float n0r = fmaf(Lr0, h0r, fmaf(-Li0, h0i, ec.x));
    float n0i = fmaf(Lr0, h0i, fmaf( Li0, h0r, ec.y));
    float n1r = fmaf(Lr1, h1r, fmaf(-Li1, h1i, ec.z));
    float n1i = fmaf(Lr1, h1i, fmaf( Li1, h1r, ec.w));
    h0r = n0r; h0i = n0i; h1r = n1r; h1i = n1i;
  }

  const uint2* up = (const uint2*)u;
  u32* xp = (u32*)xr;                 // 512 u32 per output row of 1024 u16
  size_t uidx = (size_t)(b * 4096 + c * 32) * 256 + t;
  size_t xidx = (size_t)(b * 4096 + c * 32) * 512 + t;
#pragma unroll 8
  for (int s = 0; s < 32; ++s) {
    uint2 w = up[uidx]; uidx += 256;
    float u0r = bflo(w.x), u0i = bfhi(w.x);
    float u1r = bflo(w.y), u1i = bfhi(w.y);
    float n0r = fmaf(lr0, h0r, fmaf(-li0, h0i, u0r));
    float n0i = fmaf(lr0, h0i, fmaf( li0, h0r, u0i));
    float n1r = fmaf(lr1, h1r, fmaf(-li1, h1i, u1r));
    float n1i = fmaf(lr1, h1i, fmaf( li1, h1r, u1i));
    h0r = n0r; h0i = n0i; h1r = n1r; h1i = n1i;
    // real parts -> cols 2t,2t+1 ; imag parts -> cols 512+2t,512+2t+1
    xp[xidx]       = (u32)f2bf(g0 * h0r) | ((u32)f2bf(g1 * h1r) << 16);
    xp[xidx + 256] = (u32)f2bf(g0 * h0i) | ((u32)f2bf(g1 * h1i) << 16);
    xidx += 512;
  }
}

// ---------------- launch ----------------
extern "C" void kernel_launch(void* const* d_in, const int* in_sizes, int n_in,
                              void* d_out, int out_size, void* d_ws, size_t ws_size,
                              hipStream_t stream)
{
  (void)in_sizes; (void)n_in; (void)out_size; (void)ws_size;
  const float* inputs = (const float*)d_in[0];
  const float* Wi     = (const float*)d_in[1];
  const float* bi     = (const float*)d_in[2];
  const float* Wo     = (const float*)d_in[3];
  const float* bo     = (const float*)d_in[4];
  const float* plog   = (const float*)d_in[5];

  char* ws = (char*)d_ws;
  u16*    xrA   = (u16*)(ws);                        // A_bf then xr_bf (64 MB)
  u16*    u_bf  = (u16*)(ws + 67108864ull);          // 64 MB
  u16*    Wi_bf = (u16*)(ws + 134217728ull);         // 1 MB
  u16*    Wo_bf = (u16*)(ws + 135266304ull);         // 1 MB
  float2* e_b   = (float2*)(ws + 136314880ull);      // 4 MB (8 x 128 x 512 float2)

  // 1) convert all three fp32 tensors to bf16 (one launch)
  conv3_f32_bf16<<<17408, 256, 0, stream>>>(inputs, xrA, Wi, Wi_bf, Wo, Wo_bf);

  // 2) u = X @ Wi^T + bi   (M=32768, N=1024, K=512), bf16 out
  //    128 m-tiles (16/XCD) x 8 n-tiles = 1024 blocks
  gemm_w2<1024, 512, 3, 1, 0><<<1024, 512, 0, stream>>>(xrA, Wi_bf, bi, u_bf);

  // 3) chunked complex prefix scan + gamma, write xr (bf16) over A region
  scan_chunk_end<<<dim3(128, 8), 256, 0, stream>>>(u_bf, plog, e_b);
  scan_out2<<<dim3(128, 8), 256, 0, stream>>>(u_bf, plog, e_b, xrA);

  // 4) out = relu(xr @ Wo^T + bo)  (M=32768, N=512, K=1024), fp32 out
  //    128 m-tiles (16/XCD) x 4 n-tiles = 512 blocks
  gemm_w2<512, 1024, 2, 0, 1><<<512, 512, 0, stream>>>(xrA, Wo_bf, bo, d_out);
}

// Round 2
// 254.700 us; speedup vs baseline: 1.0152x; 1.0152x over previous
//
#include <hip/hip_runtime.h>
#include <cstdint>
#include <cstddef>

typedef unsigned short u16;
typedef unsigned int   u32;

typedef short bf16x8 __attribute__((ext_vector_type(8)));
typedef float f32x4  __attribute__((ext_vector_type(4)));

// ---------------- helpers ----------------
__device__ __forceinline__ u16 f2bf(float f) {   // RNE f32 -> bf16
  u32 u = __float_as_uint(f);
  u += 0x7fffu + ((u >> 16) & 1u);
  return (u16)(u >> 16);
}
__device__ __forceinline__ float bflo(u32 w) { return __uint_as_float((w & 0xffffu) << 16); }
__device__ __forceinline__ float bfhi(u32 w) { return __uint_as_float(w & 0xffff0000u); }

#define GLB_AS(p) ((const __attribute__((address_space(1))) void*)(p))
#define LDS_AS(p) ((__attribute__((address_space(3))) void*)(p))

// ---------------- fused f32 -> bf16 convert: inputs + Wi + Wo ----------------
// quads: inputs 4194304, Wi 131072, Wo 131072 -> 17408 blocks x 256 exactly.
__global__ __launch_bounds__(256)
void conv3_f32_bf16(const float* __restrict__ in, u16* __restrict__ a,
                    const float* __restrict__ wi, u16* __restrict__ wib,
                    const float* __restrict__ wo, u16* __restrict__ wob)
{
  long i = (long)blockIdx.x * 256 + threadIdx.x;
  const float* src; u16* dst;
  if (i < 4194304L) { src = in; dst = a; }
  else if (i < 4325376L) { i -= 4194304L; src = wi; dst = wib; }
  else { i -= 4325376L; if (i >= 131072L) return; src = wo; dst = wob; }
  float4 v = ((const float4*)src)[i];
  u32 lo = (u32)f2bf(v.x) | ((u32)f2bf(v.y) << 16);
  u32 hi = (u32)f2bf(v.z) | ((u32)f2bf(v.w) << 16);
  ((uint2*)dst)[i] = make_uint2(lo, hi);
}

// ---------------- bf16 GEMM, 256x128 tile, BK=32, 512 thr, XCD-local --------
// C[m,n] = sum_k A[m,k] * W[n,k]  (A: MxK row-major, W: NxK row-major).
// R8: both gemms staged ~400 MB and both took ~49 us -> staging-LATENCY bound
// (105 cyc per 1KB DMA instr; vmcnt(0)-drain every K-step exposes full L2
// latency). Fix = T3-minimum 2-phase: double-buffered LDS, stage tile t+1
// BEFORE computing tile t, ONE barrier per step. Swizzles/fragment maps are
// byte-identical to the validated R2/R6 kernel; only the loop skeleton moved.
template<int N, int K, int LOGNB, int OUT_BF16, int RELU>
__global__ __launch_bounds__(512, 4)
void gemm_w2(const u16* __restrict__ A, const u16* __restrict__ Bw,
             const float* __restrict__ bias, void* __restrict__ Cout)
{
  __shared__ __align__(16) u16 As[2][256 * 32];   // 2 x 16 KB
  __shared__ __align__(16) u16 Bs[2][128 * 32];   // 2 x  8 KB

  const int tid  = threadIdx.x;
  const int lane = tid & 63;
  const int wave = tid >> 6;
  const int bid  = blockIdx.x;
  const int xcd  = bid & 7;
  const int s    = bid >> 3;
  const int m0 = (xcd * 16 + (s >> LOGNB)) * 256;
  const int n0 = (s & ((1 << LOGNB) - 1)) * 128;
  const int wm = (wave & 3) * 64;
  const int wn = (wave >> 2) * 64;

  f32x4 acc[4][4];
#pragma unroll
  for (int i = 0; i < 4; ++i)
#pragma unroll
    for (int j = 0; j < 4; ++j) acc[i][j] = f32x4{0.f, 0.f, 0.f, 0.f};

  // DMA staging (granule = 16 B; 4 granules per 32-k row; R2 swizzle):
  // A: 1024 granules -> 2 instrs; B: 512 granules -> 1 instr.
  const u16* Ap[2]; const u16* Bp; int ldsA[2]; int ldsB;
#pragma unroll
  for (int i = 0; i < 2; ++i) {
    int g = i * 512 + tid;
    int r = g >> 2;
    int koff = ((g & 3) ^ ((r >> 1) & 3)) << 3;
    Ap[i]   = A + (size_t)(m0 + r) * K + koff;
    ldsA[i] = (i * 512 + wave * 64) * 8;        // wave-uniform base (u16)
  }
  {
    int g = tid;
    int r = g >> 2;
    int koff = ((g & 3) ^ ((r >> 1) & 3)) << 3;
    Bp   = Bw + (size_t)(n0 + r) * K + koff;
    ldsB = (wave * 64) * 8;
  }

  // fragment granule offsets (R2-validated map)
  const int fm = lane & 15;
  const int q  = lane >> 4;
  int aoff[4], boff[4];
#pragma unroll
  for (int i = 0; i < 4; ++i) {
    int m = wm + i * 16 + fm;
    aoff[i] = (m * 4 + (q ^ ((m >> 1) & 3))) * 8;
    int n = wn + i * 16 + fm;
    boff[i] = (n * 4 + (q ^ ((n >> 1) & 3))) * 8;
  }

  auto stage = [&](int buf, int kt) {
    __builtin_amdgcn_global_load_lds(GLB_AS(Ap[0] + kt), LDS_AS(&As[buf][ldsA[0]]), 16, 0, 0);
    __builtin_amdgcn_global_load_lds(GLB_AS(Ap[1] + kt), LDS_AS(&As[buf][ldsA[1]]), 16, 0, 0);
    __builtin_amdgcn_global_load_lds(GLB_AS(Bp    + kt), LDS_AS(&Bs[buf][ldsB]),    16, 0, 0);
  };
  auto compute = [&](int buf) {
    bf16x8 af[4], bfr[4];
#pragma unroll
    for (int i = 0; i < 4; ++i) { af[i]  = *(const bf16x8*)&As[buf][aoff[i]];
                                  bfr[i] = *(const bf16x8*)&Bs[buf][boff[i]]; }
#pragma unroll
    for (int mi = 0; mi < 4; ++mi)
#pragma unroll
      for (int ni = 0; ni < 4; ++ni)
        acc[mi][ni] = __builtin_amdgcn_mfma_f32_16x16x32_bf16(af[mi], bfr[ni],
                                                              acc[mi][ni], 0, 0, 0);
  };

  constexpr int NT = K / 32;
  stage(0, 0);
  __syncthreads();                 // tile 0 visible (prologue: latency exposed once)
  int cur = 0;
  for (int t = 0; t < NT - 1; ++t) {
    stage(cur ^ 1, (t + 1) * 32);  // issue next tile's DMA FIRST
    compute(cur);                  // its latency hides under ds_read + MFMA
    __syncthreads();               // one drain per step: next buf ready, reads done
    cur ^= 1;
  }
  compute(cur);                    // last tile, no prefetch

  // epilogue: C/D layout col=lane&15, row=(lane>>4)*4+reg  (validated R1-R6)
  const int colL = lane & 15;
  const int rowQ = (lane >> 4) * 4;
#pragma unroll
  for (int mi = 0; mi < 4; ++mi) {
#pragma unroll
    for (int ni = 0; ni < 4; ++ni) {
      int col  = n0 + wn + ni * 16 + colL;
      int rowb = m0 + wm + mi * 16 + rowQ;
      float bv = bias[col];
#pragma unroll
      for (int r = 0; r < 4; ++r) {
        float v = acc[mi][ni][r] + bv;
        if (RELU) v = fmaxf(v, 0.f);
        size_t idx = (size_t)(rowb + r) * N + col;
        if (OUT_BF16) ((u16*)Cout)[idx] = f2bf(v);
        else          ((float*)Cout)[idx] = v;
      }
    }
  }
}

// ---------------- scan pass 1: per-chunk end state ----------------
// R8: 4 channels/thread, uint4 (16 B/lane) loads, 2 chunks per 256-thr block.
// 128 chunks x 32 steps. grid (64,8).
__global__ __launch_bounds__(256)
void scan_chunk_end(const u16* __restrict__ u, const float* __restrict__ plog,
                    float4* __restrict__ e)
{
  const int t  = threadIdx.x;
  const int tt = t & 127;                 // channel group: ch 4tt..4tt+3
  const int c  = blockIdx.x * 2 + (t >> 7);
  const int b  = blockIdx.y;
  float4 vl = ((const float4*)plog)[tt];
  float4 tl = ((const float4*)plog)[128 + tt];
  float vlog[4] = {vl.x, vl.y, vl.z, vl.w};
  float tlog[4] = {tl.x, tl.y, tl.z, tl.w};
  float lr[4], li[4], hr[4], hi4[4];
#pragma unroll
  for (int k = 0; k < 4; ++k) {
    float v  = expf(vlog[k]);
    float th = expf(tlog[k]);
    float mg = expf(-v);
    lr[k] = mg * cosf(th); li[k] = mg * sinf(th);
    hr[k] = 0.f; hi4[k] = 0.f;
  }
  const uint4* up = (const uint4*)u;      // 128 uint4 per row
  size_t idx = (size_t)(b * 4096 + c * 32) * 128 + tt;
#pragma unroll 8
  for (int s = 0; s < 32; ++s) {
    uint4 w = up[idx]; idx += 128;
    u32 ws[4] = {w.x, w.y, w.z, w.w};
#pragma unroll
    for (int k = 0; k < 4; ++k) {
      float ur = bflo(ws[k]), ui = bfhi(ws[k]);
      float nr = fmaf(lr[k], hr[k], fmaf(-li[k], hi4[k], ur));
      float ni = fmaf(lr[k], hi4[k], fmaf( li[k], hr[k], ui));
      hr[k] = nr; hi4[k] = ni;
    }
  }
  size_t eb = (size_t)(b * 128 + c) * 256 + 2 * tt;   // [b][c][256] float4
  e[eb]     = make_float4(hr[0], hi4[0], hr[1], hi4[1]);
  e[eb + 1] = make_float4(hr[2], hi4[2], hr[3], hi4[3]);
}

// ---------------- scan pass 2 (fused carry + output) ----------------
__global__ __launch_bounds__(256)
void scan_out2(const u16* __restrict__ u, const float* __restrict__ plog,
               const float4* __restrict__ e, u16* __restrict__ xr)
{
  const int t  = threadIdx.x;
  const int tt = t & 127;
  const int c  = blockIdx.x * 2 + (t >> 7);
  const int b  = blockIdx.y;
  float4 vl = ((const float4*)plog)[tt];
  float4 tl = ((const float4*)plog)[128 + tt];
  float4 gl = ((const float4*)plog)[256 + tt];
  float vlog[4] = {vl.x, vl.y, vl.z, vl.w};
  float tlog[4] = {tl.x, tl.y, tl.z, tl.w};
  float glog[4] = {gl.x, gl.y, gl.z, gl.w};
  float lr[4], li[4], Lr[4], Li[4], gm[4], hr[4], hi4[4];
#pragma unroll
  for (int k = 0; k < 4; ++k) {
    float v  = expf(vlog[k]);
    float th = expf(tlog[k]);
    gm[k] = expf(glog[k]);
    float mg = expf(-v);
    lr[k] = mg * cosf(th); li[k] = mg * sinf(th);
    float Lm = expf(-32.f * v);
    float La = 32.f * th;
    Lr[k] = Lm * cosf(La); Li[k] = Lm * sinf(La);   // lambda^32
    hr[k] = 0.f; hi4[k] = 0.f;
  }

  // carry across chunk-end states (L2-resident)
  size_t ebase = (size_t)(b * 128) * 256 + 2 * tt;
#pragma unroll 4
  for (int i = 0; i < c; ++i) {
    float4 e0 = e[ebase + (size_t)i * 256];
    float4 e1 = e[ebase + (size_t)i * 256 + 1];
    float n0r = fmaf(Lr[0], hr[0], fmaf(-Li[0], hi4[0], e0.x));
    float n0i = fmaf(Lr[0], hi4[0], fmaf( Li[0], hr[0], e0.y));
    float n1r = fmaf(Lr[1], hr[1], fmaf(-Li[1], hi4[1], e0.z));
    float n1i = fmaf(Lr[1], hi4[1], fmaf( Li[1], hr[1], e0.w));
    float n2r = fmaf(Lr[2], hr[2], fmaf(-Li[2], hi4[2], e1.x));
    float n2i = fmaf(Lr[2], hi4[2], fmaf( Li[2], hr[2], e1.y));
    float n3r = fmaf(Lr[3], hr[3], fmaf(-Li[3], hi4[3], e1.z));
    float n3i = fmaf(Lr[3], hi4[3], fmaf( Li[3], hr[3], e1.w));
    hr[0] = n0r; hi4[0] = n0i; hr[1] = n1r; hi4[1] = n1i;
    hr[2] = n2r; hi4[2] = n2i; hr[3] = n3r; hi4[3] = n3i;
  }

  const uint4* up = (const uint4*)u;
  uint2* xp = (uint2*)xr;                 // 256 uint2 per output row
  size_t uidx = (size_t)(b * 4096 + c * 32) * 128 + tt;
  size_t xidx = (size_t)(b * 4096 + c * 32) * 256 + tt;
#pragma unroll 8
  for (int s2 = 0; s2 < 32; ++s2) {
    uint4 w = up[uidx]; uidx += 128;
    u32 ws[4] = {w.x, w.y, w.z, w.w};
#pragma unroll
    for (int k = 0; k < 4; ++k) {
      float ur = bflo(ws[k]), ui = bfhi(ws[k]);
      float nr = fmaf(lr[k], hr[k], fmaf(-li[k], hi4[k], ur));
      float ni = fmaf(lr[k], hi4[k], fmaf( li[k], hr[k], ui));
      hr[k] = nr; hi4[k] = ni;
    }
    // reals of ch 4tt..4tt+3 -> u32 cols 2tt,2tt+1 ; imags -> +256
    u32 re0 = (u32)f2bf(gm[0] * hr[0])  | ((u32)f2bf(gm[1] * hr[1])  << 16);
    u32 re1 = (u32)f2bf(gm[2] * hr[2])  | ((u32)f2bf(gm[3] * hr[3])  << 16);
    u32 im0 = (u32)f2bf(gm[0] * hi4[0]) | ((u32)f2bf(gm[1] * hi4[1]) << 16);
    u32 im1 = (u32)f2bf(gm[2] * hi4[2]) | ((u32)f2bf(gm[3] * hi4[3]) << 16);
    xp[xidx]       = make_uint2(re0, re1);
    xp[xidx + 128] = make_uint2(im0, im1);
    xidx += 256;
  }
}

// ---------------- launch ----------------
extern "C" void kernel_launch(void* const* d_in, const int* in_sizes, int n_in,
                              void* d_out, int out_size, void* d_ws, size_t ws_size,
                              hipStream_t stream)
{
  (void)in_sizes; (void)n_in; (void)out_size; (void)ws_size;
  const float* inputs = (const float*)d_in[0];
  const float* Wi     = (const float*)d_in[1];
  const float* bi     = (const float*)d_in[2];
  const float* Wo     = (const float*)d_in[3];
  const float* bo     = (const float*)d_in[4];
  const float* plog   = (const float*)d_in[5];

  char* ws = (char*)d_ws;
  u16*    xrA   = (u16*)(ws);                        // A_bf then xr_bf (64 MB)
  u16*    u_bf  = (u16*)(ws + 67108864ull);          // 64 MB
  u16*    Wi_bf = (u16*)(ws + 134217728ull);         // 1 MB
  u16*    Wo_bf = (u16*)(ws + 135266304ull);         // 1 MB
  float4* e_b   = (float4*)(ws + 136314880ull);      // 4 MB (8 x 128 x 256 float4)

  // 1) convert all three fp32 tensors to bf16 (one launch)
  conv3_f32_bf16<<<17408, 256, 0, stream>>>(inputs, xrA, Wi, Wi_bf, Wo, Wo_bf);

  // 2) u = X @ Wi^T + bi   (M=32768, N=1024, K=512), bf16 out
  //    128 m-tiles (16/XCD) x 8 n-tiles = 1024 blocks
  gemm_w2<1024, 512, 3, 1, 0><<<1024, 512, 0, stream>>>(xrA, Wi_bf, bi, u_bf);

  // 3) chunked complex prefix scan + gamma, write xr (bf16) over A region
  scan_chunk_end<<<dim3(64, 8), 256, 0, stream>>>(u_bf, plog, e_b);
  scan_out2<<<dim3(64, 8), 256, 0, stream>>>(u_bf, plog, e_b, xrA);

  // 4) out = relu(xr @ Wo^T + bo)  (M=32768, N=512, K=1024), fp32 out
  //    128 m-tiles (16/XCD) x 4 n-tiles = 512 blocks
  gemm_w2<512, 1024, 2, 0, 1><<<512, 512, 0, stream>>>(xrA, Wo_bf, bo, d_out);
}

// Round 3
// 251.913 us; speedup vs baseline: 1.0265x; 1.0111x over previous
//
#include <hip/hip_runtime.h>
#include <cstdint>
#include <cstddef>

typedef unsigned short u16;
typedef unsigned int   u32;

typedef short bf16x8 __attribute__((ext_vector_type(8)));
typedef float f32x4  __attribute__((ext_vector_type(4)));

// ---------------- helpers ----------------
__device__ __forceinline__ u16 f2bf(float f) {   // RNE f32 -> bf16
  u32 u = __float_as_uint(f);
  u += 0x7fffu + ((u >> 16) & 1u);
  return (u16)(u >> 16);
}
__device__ __forceinline__ float bflo(u32 w) { return __uint_as_float((w & 0xffffu) << 16); }
__device__ __forceinline__ float bfhi(u32 w) { return __uint_as_float(w & 0xffff0000u); }

#define GLB_AS(p) ((const __attribute__((address_space(1))) void*)(p))
#define LDS_AS(p) ((__attribute__((address_space(3))) void*)(p))

// ---------------- fused f32 -> bf16 convert: inputs + Wi + Wo ----------------
// quads: inputs 4194304, Wi 131072, Wo 131072 -> 17408 blocks x 256 exactly.
__global__ __launch_bounds__(256)
void conv3_f32_bf16(const float* __restrict__ in, u16* __restrict__ a,
                    const float* __restrict__ wi, u16* __restrict__ wib,
                    const float* __restrict__ wo, u16* __restrict__ wob)
{
  long i = (long)blockIdx.x * 256 + threadIdx.x;
  const float* src; u16* dst;
  if (i < 4194304L) { src = in; dst = a; }
  else if (i < 4325376L) { i -= 4194304L; src = wi; dst = wib; }
  else { i -= 4325376L; if (i >= 131072L) return; src = wo; dst = wob; }
  float4 v = ((const float4*)src)[i];
  u32 lo = (u32)f2bf(v.x) | ((u32)f2bf(v.y) << 16);
  u32 hi = (u32)f2bf(v.z) | ((u32)f2bf(v.w) << 16);
  ((uint2*)dst)[i] = make_uint2(lo, hi);
}

// ---------------- bf16 GEMM, 256x128 tile, BK=32, 512 thr, XCD-local --------
// C[m,n] = sum_k A[m,k] * W[n,k]  (A: MxK row-major, W: NxK row-major).
// R9: R8's 2-phase dbuf was neutral (49.3->48.5us) -- __syncthreads() drains
// vmcnt(0) every step, so the prefetch is drained at the very barrier meant
// to hide it (guide m99/m100). The gain of pipelining IS the counted vmcnt
// (m218). This version: 3-buffer rotation, depth-2 prefetch, ONE raw
// s_barrier per step, per-wave s_waitcnt vmcnt(3) (never 0 in the loop).
// Safety of the single barrier: stage(t+2) overwrites the buffer read at
// step t-1; those ds_reads were consumed by MFMAs before each wave could
// reach this step's barrier. vmcnt(3)+s_barrier => ALL waves' tile-t DMA
// landed. Swizzles / fragment maps / epilogue are the validated R2/R6 ones.
template<int N, int K, int LOGNB, int OUT_BF16, int RELU>
__global__ __launch_bounds__(512, 4)
void gemm_w2(const u16* __restrict__ A, const u16* __restrict__ Bw,
             const float* __restrict__ bias, void* __restrict__ Cout)
{
  __shared__ __align__(16) u16 As[3][256 * 32];   // 3 x 16 KB
  __shared__ __align__(16) u16 Bs[3][128 * 32];   // 3 x  8 KB  (72 KB total)

  const int tid  = threadIdx.x;
  const int lane = tid & 63;
  const int wave = tid >> 6;
  const int bid  = blockIdx.x;
  const int xcd  = bid & 7;
  const int s    = bid >> 3;
  const int m0 = (xcd * 16 + (s >> LOGNB)) * 256;
  const int n0 = (s & ((1 << LOGNB) - 1)) * 128;
  const int wm = (wave & 3) * 64;
  const int wn = (wave >> 2) * 64;

  f32x4 acc[4][4];
#pragma unroll
  for (int i = 0; i < 4; ++i)
#pragma unroll
    for (int j = 0; j < 4; ++j) acc[i][j] = f32x4{0.f, 0.f, 0.f, 0.f};

  // DMA staging (granule = 16 B; 4 granules per 32-k row; R2 swizzle):
  // A: 1024 granules -> 2 instrs; B: 512 granules -> 1 instr. 3 vmem/step/wave.
  const u16* Ap[2]; const u16* Bp; int ldsA[2]; int ldsB;
#pragma unroll
  for (int i = 0; i < 2; ++i) {
    int g = i * 512 + tid;
    int r = g >> 2;
    int koff = ((g & 3) ^ ((r >> 1) & 3)) << 3;
    Ap[i]   = A + (size_t)(m0 + r) * K + koff;
    ldsA[i] = (i * 512 + wave * 64) * 8;        // wave-uniform base (u16)
  }
  {
    int g = tid;
    int r = g >> 2;
    int koff = ((g & 3) ^ ((r >> 1) & 3)) << 3;
    Bp   = Bw + (size_t)(n0 + r) * K + koff;
    ldsB = (wave * 64) * 8;
  }

  // fragment granule offsets (R2-validated map)
  const int fm = lane & 15;
  const int q  = lane >> 4;
  int aoff[4], boff[4];
#pragma unroll
  for (int i = 0; i < 4; ++i) {
    int m = wm + i * 16 + fm;
    aoff[i] = (m * 4 + (q ^ ((m >> 1) & 3))) * 8;
    int n = wn + i * 16 + fm;
    boff[i] = (n * 4 + (q ^ ((n >> 1) & 3))) * 8;
  }

  auto stage = [&](int buf, int kt) {
    __builtin_amdgcn_global_load_lds(GLB_AS(Ap[0] + kt), LDS_AS(&As[buf][ldsA[0]]), 16, 0, 0);
    __builtin_amdgcn_global_load_lds(GLB_AS(Ap[1] + kt), LDS_AS(&As[buf][ldsA[1]]), 16, 0, 0);
    __builtin_amdgcn_global_load_lds(GLB_AS(Bp    + kt), LDS_AS(&Bs[buf][ldsB]),    16, 0, 0);
  };
  auto compute = [&](int buf) {
    bf16x8 af[4], bfr[4];
#pragma unroll
    for (int i = 0; i < 4; ++i) { af[i]  = *(const bf16x8*)&As[buf][aoff[i]];
                                  bfr[i] = *(const bf16x8*)&Bs[buf][boff[i]]; }
#pragma unroll
    for (int mi = 0; mi < 4; ++mi)
#pragma unroll
      for (int ni = 0; ni < 4; ++ni)
        acc[mi][ni] = __builtin_amdgcn_mfma_f32_16x16x32_bf16(af[mi], bfr[ni],
                                                              acc[mi][ni], 0, 0, 0);
  };

  constexpr int NT = K / 32;
  stage(0, 0);
  stage(1, 32);                       // depth-2 prefetch in flight
#pragma unroll
  for (int t = 0; t < NT - 1; ++t) {
    // tile t landed when <=3 of our loads remain (tile t+1's) -- never drain to 0
    asm volatile("s_waitcnt vmcnt(3)" ::: "memory");
    __builtin_amdgcn_s_barrier();     // all waves' tile-t DMA landed; t-1 reads done
    if (t + 2 < NT) stage((t + 2) % 3, (t + 2) * 32);
    compute(t % 3);
  }
  asm volatile("s_waitcnt vmcnt(0)" ::: "memory");
  __builtin_amdgcn_s_barrier();
  compute((NT - 1) % 3);

  // epilogue: C/D layout col=lane&15, row=(lane>>4)*4+reg  (validated R1-R6)
  const int colL = lane & 15;
  const int rowQ = (lane >> 4) * 4;
#pragma unroll
  for (int mi = 0; mi < 4; ++mi) {
#pragma unroll
    for (int ni = 0; ni < 4; ++ni) {
      int col  = n0 + wn + ni * 16 + colL;
      int rowb = m0 + wm + mi * 16 + rowQ;
      float bv = bias[col];
#pragma unroll
      for (int r = 0; r < 4; ++r) {
        float v = acc[mi][ni][r] + bv;
        if (RELU) v = fmaxf(v, 0.f);
        size_t idx = (size_t)(rowb + r) * N + col;
        if (OUT_BF16) ((u16*)Cout)[idx] = f2bf(v);
        else          ((float*)Cout)[idx] = v;
      }
    }
  }
}

// ---------------- scan pass 1: per-chunk end state ----------------
// 4 channels/thread, uint4 (16 B/lane) loads, 2 chunks per 256-thr block.
// 128 chunks x 32 steps. grid (64,8).
__global__ __launch_bounds__(256)
void scan_chunk_end(const u16* __restrict__ u, const float* __restrict__ plog,
                    float4* __restrict__ e)
{
  const int t  = threadIdx.x;
  const int tt = t & 127;                 // channel group: ch 4tt..4tt+3
  const int c  = blockIdx.x * 2 + (t >> 7);
  const int b  = blockIdx.y;
  float4 vl = ((const float4*)plog)[tt];
  float4 tl = ((const float4*)plog)[128 + tt];
  float vlog[4] = {vl.x, vl.y, vl.z, vl.w};
  float tlog[4] = {tl.x, tl.y, tl.z, tl.w};
  float lr[4], li[4], hr[4], hi4[4];
#pragma unroll
  for (int k = 0; k < 4; ++k) {
    float v  = expf(vlog[k]);
    float th = expf(tlog[k]);
    float mg = expf(-v);
    lr[k] = mg * cosf(th); li[k] = mg * sinf(th);
    hr[k] = 0.f; hi4[k] = 0.f;
  }
  const uint4* up = (const uint4*)u;      // 128 uint4 per row
  size_t idx = (size_t)(b * 4096 + c * 32) * 128 + tt;
#pragma unroll 8
  for (int s = 0; s < 32; ++s) {
    uint4 w = up[idx]; idx += 128;
    u32 ws[4] = {w.x, w.y, w.z, w.w};
#pragma unroll
    for (int k = 0; k < 4; ++k) {
      float ur = bflo(ws[k]), ui = bfhi(ws[k]);
      float nr = fmaf(lr[k], hr[k], fmaf(-li[k], hi4[k], ur));
      float ni = fmaf(lr[k], hi4[k], fmaf( li[k], hr[k], ui));
      hr[k] = nr; hi4[k] = ni;
    }
  }
  size_t eb = (size_t)(b * 128 + c) * 256 + 2 * tt;   // [b][c][256] float4
  e[eb]     = make_float4(hr[0], hi4[0], hr[1], hi4[1]);
  e[eb + 1] = make_float4(hr[2], hi4[2], hr[3], hi4[3]);
}

// ---------------- scan pass 2 (fused carry + output) ----------------
__global__ __launch_bounds__(256)
void scan_out2(const u16* __restrict__ u, const float* __restrict__ plog,
               const float4* __restrict__ e, u16* __restrict__ xr)
{
  const int t  = threadIdx.x;
  const int tt = t & 127;
  const int c  = blockIdx.x * 2 + (t >> 7);
  const int b  = blockIdx.y;
  float4 vl = ((const float4*)plog)[tt];
  float4 tl = ((const float4*)plog)[128 + tt];
  float4 gl = ((const float4*)plog)[256 + tt];
  float vlog[4] = {vl.x, vl.y, vl.z, vl.w};
  float tlog[4] = {tl.x, tl.y, tl.z, tl.w};
  float glog[4] = {gl.x, gl.y, gl.z, gl.w};
  float lr[4], li[4], Lr[4], Li[4], gm[4], hr[4], hi4[4];
#pragma unroll
  for (int k = 0; k < 4; ++k) {
    float v  = expf(vlog[k]);
    float th = expf(tlog[k]);
    gm[k] = expf(glog[k]);
    float mg = expf(-v);
    lr[k] = mg * cosf(th); li[k] = mg * sinf(th);
    float Lm = expf(-32.f * v);
    float La = 32.f * th;
    Lr[k] = Lm * cosf(La); Li[k] = Lm * sinf(La);   // lambda^32
    hr[k] = 0.f; hi4[k] = 0.f;
  }

  // carry across chunk-end states (L2-resident)
  size_t ebase = (size_t)(b * 128) * 256 + 2 * tt;
#pragma unroll 4
  for (int i = 0; i < c; ++i) {
    float4 e0 = e[ebase + (size_t)i * 256];
    float4 e1 = e[ebase + (size_t)i * 256 + 1];
    float n0r = fmaf(Lr[0], hr[0], fmaf(-Li[0], hi4[0], e0.x));
    float n0i = fmaf(Lr[0], hi4[0], fmaf( Li[0], hr[0], e0.y));
    float n1r = fmaf(Lr[1], hr[1], fmaf(-Li[1], hi4[1], e0.z));
    float n1i = fmaf(Lr[1], hi4[1], fmaf( Li[1], hr[1], e0.w));
    float n2r = fmaf(Lr[2], hr[2], fmaf(-Li[2], hi4[2], e1.x));
    float n2i = fmaf(Lr[2], hi4[2], fmaf( Li[2], hr[2], e1.y));
    float n3r = fmaf(Lr[3], hr[3], fmaf(-Li[3], hi4[3], e1.z));
    float n3i = fmaf(Lr[3], hi4[3], fmaf( Li[3], hr[3], e1.w));
    hr[0] = n0r; hi4[0] = n0i; hr[1] = n1r; hi4[1] = n1i;
    hr[2] = n2r; hi4[2] = n2i; hr[3] = n3r; hi4[3] = n3i;
  }

  const uint4* up = (const uint4*)u;
  uint2* xp = (uint2*)xr;                 // 256 uint2 per output row
  size_t uidx = (size_t)(b * 4096 + c * 32) * 128 + tt;
  size_t xidx = (size_t)(b * 4096 + c * 32) * 256 + tt;
#pragma unroll 8
  for (int s2 = 0; s2 < 32; ++s2) {
    uint4 w = up[uidx]; uidx += 128;
    u32 ws[4] = {w.x, w.y, w.z, w.w};
#pragma unroll
    for (int k = 0; k < 4; ++k) {
      float ur = bflo(ws[k]), ui = bfhi(ws[k]);
      float nr = fmaf(lr[k], hr[k], fmaf(-li[k], hi4[k], ur));
      float ni = fmaf(lr[k], hi4[k], fmaf( li[k], hr[k], ui));
      hr[k] = nr; hi4[k] = ni;
    }
    // reals of ch 4tt..4tt+3 -> u32 cols 2tt,2tt+1 ; imags -> +256
    u32 re0 = (u32)f2bf(gm[0] * hr[0])  | ((u32)f2bf(gm[1] * hr[1])  << 16);
    u32 re1 = (u32)f2bf(gm[2] * hr[2])  | ((u32)f2bf(gm[3] * hr[3])  << 16);
    u32 im0 = (u32)f2bf(gm[0] * hi4[0]) | ((u32)f2bf(gm[1] * hi4[1]) << 16);
    u32 im1 = (u32)f2bf(gm[2] * hi4[2]) | ((u32)f2bf(gm[3] * hi4[3]) << 16);
    xp[xidx]       = make_uint2(re0, re1);
    xp[xidx + 128] = make_uint2(im0, im1);
    xidx += 256;
  }
}

// ---------------- launch ----------------
extern "C" void kernel_launch(void* const* d_in, const int* in_sizes, int n_in,
                              void* d_out, int out_size, void* d_ws, size_t ws_size,
                              hipStream_t stream)
{
  (void)in_sizes; (void)n_in; (void)out_size; (void)ws_size;
  const float* inputs = (const float*)d_in[0];
  const float* Wi     = (const float*)d_in[1];
  const float* bi     = (const float*)d_in[2];
  const float* Wo     = (const float*)d_in[3];
  const float* bo     = (const float*)d_in[4];
  const float* plog   = (const float*)d_in[5];

  char* ws = (char*)d_ws;
  u16*    xrA   = (u16*)(ws);                        // A_bf then xr_bf (64 MB)
  u16*    u_bf  = (u16*)(ws + 67108864ull);          // 64 MB
  u16*    Wi_bf = (u16*)(ws + 134217728ull);         // 1 MB
  u16*    Wo_bf = (u16*)(ws + 135266304ull);         // 1 MB
  float4* e_b   = (float4*)(ws + 136314880ull);      // 4 MB (8 x 128 x 256 float4)

  // 1) convert all three fp32 tensors to bf16 (one launch)
  conv3_f32_bf16<<<17408, 256, 0, stream>>>(inputs, xrA, Wi, Wi_bf, Wo, Wo_bf);

  // 2) u = X @ Wi^T + bi   (M=32768, N=1024, K=512), bf16 out
  //    128 m-tiles (16/XCD) x 8 n-tiles = 1024 blocks
  gemm_w2<1024, 512, 3, 1, 0><<<1024, 512, 0, stream>>>(xrA, Wi_bf, bi, u_bf);

  // 3) chunked complex prefix scan + gamma, write xr (bf16) over A region
  scan_chunk_end<<<dim3(64, 8), 256, 0, stream>>>(u_bf, plog, e_b);
  scan_out2<<<dim3(64, 8), 256, 0, stream>>>(u_bf, plog, e_b, xrA);

  // 4) out = relu(xr @ Wo^T + bo)  (M=32768, N=512, K=1024), fp32 out
  //    128 m-tiles (16/XCD) x 4 n-tiles = 512 blocks
  gemm_w2<512, 1024, 2, 0, 1><<<512, 512, 0, stream>>>(xrA, Wo_bf, bo, d_out);
}